// Round 11
// baseline (124.155 us; speedup 1.0000x reference)
//
#include <hip/hip_runtime.h>

#define T_ 7
#define H_ 48
#define W_ 48
#define P_ 16128      // T_*H_*W_
#define HW_ 2304

typedef __attribute__((ext_vector_type(8))) short short8;
typedef __attribute__((ext_vector_type(4))) float f32x4;
typedef __attribute__((ext_vector_type(2))) float f32x2;
typedef __attribute__((ext_vector_type(4))) unsigned u32x4;

__device__ __forceinline__ unsigned short f2bf(float f) {
  union { float f; unsigned u; } x{f};
  unsigned r = x.u + 0x7FFFu + ((x.u >> 16) & 1u);
  return (unsigned short)(r >> 16);
}
__device__ __forceinline__ float blo(unsigned u) {
  union { unsigned u; float f; } x{u << 16};
  return x.f;
}
__device__ __forceinline__ float bhi(unsigned u) {
  union { unsigned u; float f; } x{u & 0xFFFF0000u};
  return x.f;
}
__device__ __forceinline__ unsigned pack2(float a, float b) {
  return (unsigned)f2bf(a) | ((unsigned)f2bf(b) << 16);
}
__device__ __forceinline__ int xcd_swz(int bid, int nwg) {
  int cpx = nwg >> 3;
  return (bid & 7) * cpx + (bid >> 3);
}

struct Wgt { short8 b00, b01, b10, b11, b20, b21, b30, b31; };

__device__ __forceinline__ Wgt load_w(const unsigned short* base, int k, int lane) {
  const unsigned short* wp = base + (size_t)k * 4096 + lane * 8;
  Wgt w;
  w.b00 = *(const short8*)(wp);
  w.b01 = *(const short8*)(wp + 512);
  w.b10 = *(const short8*)(wp + 1024);
  w.b11 = *(const short8*)(wp + 1536);
  w.b20 = *(const short8*)(wp + 2048);
  w.b21 = *(const short8*)(wp + 2560);
  w.b30 = *(const short8*)(wp + 3072);
  w.b31 = *(const short8*)(wp + 3584);
  return w;
}

// non-temporal weight load: bypass L1 so the streaming weights don't evict
// the gather window (the whole point of this round)
__device__ __forceinline__ Wgt load_w_nt(const unsigned short* base, int k, int lane) {
  const short8* wp = (const short8*)(base + (size_t)k * 4096 + lane * 8);
  Wgt w;
  w.b00 = __builtin_nontemporal_load(wp);
  w.b01 = __builtin_nontemporal_load(wp + 64);
  w.b10 = __builtin_nontemporal_load(wp + 128);
  w.b11 = __builtin_nontemporal_load(wp + 192);
  w.b20 = __builtin_nontemporal_load(wp + 256);
  w.b21 = __builtin_nontemporal_load(wp + 320);
  w.b30 = __builtin_nontemporal_load(wp + 384);
  w.b31 = __builtin_nontemporal_load(wp + 448);
  return w;
}

__device__ __forceinline__ void mfma8(const Wgt& W, short8 af0, short8 af1,
                                      f32x4& c0, f32x4& c1, f32x4& c2, f32x4& c3) {
  c0 = __builtin_amdgcn_mfma_f32_16x16x32_bf16(af0, W.b00, c0, 0, 0, 0);
  c0 = __builtin_amdgcn_mfma_f32_16x16x32_bf16(af1, W.b01, c0, 0, 0, 0);
  c1 = __builtin_amdgcn_mfma_f32_16x16x32_bf16(af0, W.b10, c1, 0, 0, 0);
  c1 = __builtin_amdgcn_mfma_f32_16x16x32_bf16(af1, W.b11, c1, 0, 0, 0);
  c2 = __builtin_amdgcn_mfma_f32_16x16x32_bf16(af0, W.b20, c2, 0, 0, 0);
  c2 = __builtin_amdgcn_mfma_f32_16x16x32_bf16(af1, W.b21, c2, 0, 0, 0);
  c3 = __builtin_amdgcn_mfma_f32_16x16x32_bf16(af0, W.b30, c3, 0, 0, 0);
  c3 = __builtin_amdgcn_mfma_f32_16x16x32_bf16(af1, W.b31, c3, 0, 0, 0);
}

// ---------- x [64][P] fp32 -> x_clb [P][64] bf16 ----------
__global__ void k_prep_x(const float* __restrict__ in, unsigned short* __restrict__ outb) {
  __shared__ float tile[64][65];
  int p0 = blockIdx.x * 64;
  int l = threadIdx.x & 63;
  int g = threadIdx.x >> 6;
#pragma unroll
  for (int i = 0; i < 16; ++i) {
    int c = g * 16 + i;
    tile[c][l] = in[c * P_ + p0 + l];
  }
  __syncthreads();
#pragma unroll
  for (int i = 0; i < 16; ++i) {
    int p = g * 16 + i;
    outb[(p0 + p) * 64 + l] = f2bf(tile[l][p]);
  }
}

// ---------- weights [OC][64][27] fp32 -> fragment-swizzled bf16 ----------
__global__ void k_prep_w4(const float* __restrict__ s0, const float* __restrict__ s1,
                          const float* __restrict__ s2, const float* __restrict__ s3,
                          unsigned short* __restrict__ d0, unsigned short* __restrict__ d1,
                          unsigned short* __restrict__ d2, unsigned short* __restrict__ d3) {
  int y = blockIdx.y;
  const float* w = (y == 0) ? s0 : (y == 1) ? s1 : (y == 2) ? s2 : s3;
  unsigned short* wt = (y == 0) ? d0 : (y == 1) ? d1 : (y == 2) ? d2 : d3;
  int OC = (y < 2) ? 54 : 64;
  int idx = blockIdx.x * 256 + threadIdx.x;   // < 110592
  int j = idx & 7;
  int l = (idx >> 3) & 63;
  int kc = (idx >> 9) & 1;
  int nt = (idx >> 10) & 3;
  int k = idx >> 12;
  int o = nt * 16 + (l & 15);
  int c = kc * 32 + (l >> 4) * 8 + j;
  wt[idx] = (o < OC) ? f2bf(w[(o * 64 + c) * 27 + k]) : (unsigned short)0;
}

// ---------- offset conv (R8-proven, unchanged) ----------
__global__ __launch_bounds__(256) void k_off4w(const unsigned short* __restrict__ xclb,
                                               const unsigned short* __restrict__ wAs,
                                               const float* __restrict__ boff,
                                               float* __restrict__ offt2) {
  __shared__ f32x4 red[4][4][64];
  int p0 = xcd_swz(blockIdx.x, gridDim.x) * 32;
  int t = p0 / HW_;
  int r0 = p0 - t * HW_;
  int h0r = r0 / W_;
  int w0s = r0 - h0r * W_;
  int h1r = h0r + (w0s == 32 ? 1 : 0);
  int w1s = (w0s == 32) ? 0 : w0s + 16;
  int tid = threadIdx.x;
  int lane = tid & 63, wid = tid >> 6;
  int pt = lane & 15, grp = lane >> 4;

  f32x4 zacc{0.f, 0.f, 0.f, 0.f};
  f32x4 aA0 = zacc, aA1 = zacc, aA2 = zacc, aA3 = zacc;
  f32x4 aB0 = zacc, aB1 = zacc, aB2 = zacc, aB3 = zacc;
  const short8 zero8{0, 0, 0, 0, 0, 0, 0, 0};
  int kbeg = wid * 7;

#pragma unroll
  for (int kk = 0; kk < 7; ++kk) {
    int kraw = kbeg + kk;
    int k = min(kraw, 26);
    int kt = k / 9;
    int r9 = k - kt * 9;
    int kh = r9 / 3;
    int kw = r9 - (r9 / 3) * 3;
    int t2 = t + kt - 1;
    bool tok = (kraw < 27) & ((unsigned)t2 < (unsigned)T_);
    int t2c = min(max(t2, 0), T_ - 1);

    Wgt W = load_w(wAs, k, lane);
    {
      int h2 = h0r + kh - 1;
      int w2 = w0s + pt + kw - 1;
      bool ok = tok & ((unsigned)h2 < (unsigned)H_) & ((unsigned)w2 < (unsigned)W_);
      int h2c = min(max(h2, 0), H_ - 1);
      int w2c = min(max(w2, 0), W_ - 1);
      const unsigned short* ap = xclb + ((size_t)(t2c * HW_ + h2c * W_ + w2c) * 64 + grp * 8);
      short8 a0 = *(const short8*)ap;
      short8 a1 = *(const short8*)(ap + 32);
      a0 = ok ? a0 : zero8;
      a1 = ok ? a1 : zero8;
      mfma8(W, a0, a1, aA0, aA1, aA2, aA3);
    }
    {
      int h2 = h1r + kh - 1;
      int w2 = w1s + pt + kw - 1;
      bool ok = tok & ((unsigned)h2 < (unsigned)H_) & ((unsigned)w2 < (unsigned)W_);
      int h2c = min(max(h2, 0), H_ - 1);
      int w2c = min(max(w2, 0), W_ - 1);
      const unsigned short* ap = xclb + ((size_t)(t2c * HW_ + h2c * W_ + w2c) * 64 + grp * 8);
      short8 a0 = *(const short8*)ap;
      short8 a1 = *(const short8*)(ap + 32);
      a0 = ok ? a0 : zero8;
      a1 = ok ? a1 : zero8;
      mfma8(W, a0, a1, aB0, aB1, aB2, aB3);
    }
  }

  int oc = wid * 16 + pt;
  float bb = (oc < 54) ? boff[oc] : 0.f;
  int kidx = oc >> 1, d = oc & 1;

  red[wid][0][lane] = aA0;
  red[wid][1][lane] = aA1;
  red[wid][2][lane] = aA2;
  red[wid][3][lane] = aA3;
  __syncthreads();
  {
    f32x4 s = red[0][wid][lane];
    s = s + red[1][wid][lane];
    s = s + red[2][wid][lane];
    s = s + red[3][wid][lane];
    if (oc < 54) {
#pragma unroll
      for (int r = 0; r < 4; ++r) {
        int p = p0 + grp * 4 + r;
        offt2[((size_t)kidx * P_ + p) * 2 + d] = s[r] + bb;
      }
    }
  }
  __syncthreads();
  red[wid][0][lane] = aB0;
  red[wid][1][lane] = aB1;
  red[wid][2][lane] = aB2;
  red[wid][3][lane] = aB3;
  __syncthreads();
  {
    f32x4 s = red[0][wid][lane];
    s = s + red[1][wid][lane];
    s = s + red[2][wid][lane];
    s = s + red[3][wid][lane];
    if (oc < 54) {
#pragma unroll
      for (int r = 0; r < 4; ++r) {
        int p = p0 + 16 + grp * 4 + r;
        offt2[((size_t)kidx * P_ + p) * 2 + d] = s[r] + bb;
      }
    }
  }
}

// ---------- deformable sample + conv: L1-resident window version ----------
// 1 block/CU (dummy dynamic LDS), kt-outer phase-locked, nt weight/offset loads.
// Per-slot numerics identical to R8's k_samp4w.
template <int MODE>
__global__ __launch_bounds__(256) void k_samp_l1(
    const unsigned short* __restrict__ xclb, const float* __restrict__ offt2,
    const unsigned short* __restrict__ wBs, const float* __restrict__ bias,
    const float* __restrict__ resid, float* __restrict__ out32,
    unsigned short* __restrict__ outb) {
  extern __shared__ char occupancy_pad[];       // never touched; limits to 1 block/CU
  (void)occupancy_pad;
  __shared__ f32x4 red[4][4][64];
  __shared__ unsigned short sA[4][2][16][72];
  int p0 = xcd_swz(blockIdx.x, gridDim.x) * 32;
  int t = p0 / HW_;
  int r0 = p0 - t * HW_;
  int h0r = r0 / W_;
  int w0s = r0 - h0r * W_;
  int h1r = h0r + (w0s == 32 ? 1 : 0);
  int w1s = (w0s == 32) ? 0 : w0s + 16;
  int tid = threadIdx.x;
  int lane = tid & 63, wid = tid >> 6;
  int pt = lane & 15, grp = lane >> 4;

  f32x4 zacc{0.f, 0.f, 0.f, 0.f};
  f32x4 aA0 = zacc, aA1 = zacc, aA2 = zacc, aA3 = zacc;
  f32x4 aB0 = zacc, aB1 = zacc, aB2 = zacc, aB3 = zacc;

  for (int kt = 0; kt < 3; ++kt) {
    int t2 = t + kt - 1;
    if ((unsigned)t2 < (unsigned)T_) {          // block-uniform
      // rotation-balanced tap units: wave wid handles jc % 4 == (wid+kt)%4
      int cls = (wid + kt) & 3;
#pragma unroll
      for (int u = 0; u < 3; ++u) {
        int jc = cls + 4 * u;
        if (jc < 9) {                           // wave-uniform
          int kh = jc / 3;
          int kw = jc - (jc / 3) * 3;
          int kk = kt * 9 + jc;
          Wgt W = load_w_nt(wBs, kk, lane);
#pragma unroll
          for (int f = 0; f < 2; ++f) {
            int hrow = f ? h1r : h0r;
            int wst = f ? w1s : w0s;
            f32x2 o2 = __builtin_nontemporal_load(
                (const f32x2*)(offt2 + ((size_t)kk * P_ + p0 + f * 16 + pt) * 2));
            float ph = (float)(hrow + kh - 1) + o2.x;
            float pw = (float)(wst + pt + kw - 1) + o2.y;
            float hf = floorf(ph), wf = floorf(pw);
            float lh = ph - hf, lw = pw - wf;
            int h0 = (int)hf, w0i = (int)wf;
            int h1 = h0 + 1, w1 = w0i + 1;
            bool h0ok = ((unsigned)h0 < (unsigned)H_), h1ok = ((unsigned)h1 < (unsigned)H_);
            bool w0ok = ((unsigned)w0i < (unsigned)W_), w1ok = ((unsigned)w1 < (unsigned)W_);
            int h0c = min(max(h0, 0), H_ - 1), h1c = min(max(h1, 0), H_ - 1);
            int w0c = min(max(w0i, 0), W_ - 1), w1c = min(max(w1, 0), W_ - 1);
            float omlh = 1.f - lh, omlw = 1.f - lw;
            float g00 = (h0ok & w0ok) ? omlh * omlw : 0.f;
            float g01 = (h0ok & w1ok) ? omlh * lw : 0.f;
            float g10 = (h1ok & w0ok) ? lh * omlw : 0.f;
            float g11 = (h1ok & w1ok) ? lh * lw : 0.f;

            // gathers stay CACHED — the L1-resident window is the optimization
            const unsigned short* bt = xclb + (size_t)(t2 * HW_) * 64 + grp * 16;
            int i00 = (h0c * W_ + w0c) * 64;
            int i01 = (h0c * W_ + w1c) * 64;
            int i10 = (h1c * W_ + w0c) * 64;
            int i11 = (h1c * W_ + w1c) * 64;
            u32x4 A0 = *(const u32x4*)(bt + i00), A1 = *(const u32x4*)(bt + i00 + 8);
            u32x4 B0 = *(const u32x4*)(bt + i01), B1 = *(const u32x4*)(bt + i01 + 8);
            u32x4 C0 = *(const u32x4*)(bt + i10), C1 = *(const u32x4*)(bt + i10 + 8);
            u32x4 D0 = *(const u32x4*)(bt + i11), D1 = *(const u32x4*)(bt + i11 + 8);

#define LERPU(a, b, c, d)                                                   \
  pack2(g00 * blo(a) + g01 * blo(b) + g10 * blo(c) + g11 * blo(d),          \
        g00 * bhi(a) + g01 * bhi(b) + g10 * bhi(c) + g11 * bhi(d))
            u32x4 v0, v1;
            v0[0] = LERPU(A0[0], B0[0], C0[0], D0[0]);
            v0[1] = LERPU(A0[1], B0[1], C0[1], D0[1]);
            v0[2] = LERPU(A0[2], B0[2], C0[2], D0[2]);
            v0[3] = LERPU(A0[3], B0[3], C0[3], D0[3]);
            v1[0] = LERPU(A1[0], B1[0], C1[0], D1[0]);
            v1[1] = LERPU(A1[1], B1[1], C1[1], D1[1]);
            v1[2] = LERPU(A1[2], B1[2], C1[2], D1[2]);
            v1[3] = LERPU(A1[3], B1[3], C1[3], D1[3]);
#undef LERPU

            __builtin_amdgcn_wave_barrier();
            *(u32x4*)&sA[wid][f][pt][grp * 16] = v0;
            *(u32x4*)&sA[wid][f][pt][grp * 16 + 8] = v1;
            __builtin_amdgcn_wave_barrier();    // same-wave LDS in-order
            short8 af0 = *(const short8*)&sA[wid][f][pt][grp * 8];
            short8 af1 = *(const short8*)&sA[wid][f][pt][32 + grp * 8];
            __builtin_amdgcn_wave_barrier();

            if (f == 0) mfma8(W, af0, af1, aA0, aA1, aA2, aA3);
            else        mfma8(W, af0, af1, aB0, aB1, aB2, aB3);
          }
        }
      }
    }
    __syncthreads();                            // phase-lock: one window live
  }

  int ch = wid * 16 + pt;
  float bb = bias[ch];

  red[wid][0][lane] = aA0;
  red[wid][1][lane] = aA1;
  red[wid][2][lane] = aA2;
  red[wid][3][lane] = aA3;
  __syncthreads();
  {
    f32x4 s = red[0][wid][lane];
    s = s + red[1][wid][lane];
    s = s + red[2][wid][lane];
    s = s + red[3][wid][lane];
#pragma unroll
    for (int r = 0; r < 4; ++r) {
      int p = p0 + grp * 4 + r;
      float v = s[r] + bb;
      if (MODE == 0) {
        v = (v >= 0.f) ? v : 0.1f * v;
        outb[(size_t)p * 64 + ch] = f2bf(v);
      } else {
        out32[(size_t)ch * P_ + p] = v + resid[(size_t)ch * P_ + p];
      }
    }
  }
  __syncthreads();
  red[wid][0][lane] = aB0;
  red[wid][1][lane] = aB1;
  red[wid][2][lane] = aB2;
  red[wid][3][lane] = aB3;
  __syncthreads();
  {
    f32x4 s = red[0][wid][lane];
    s = s + red[1][wid][lane];
    s = s + red[2][wid][lane];
    s = s + red[3][wid][lane];
#pragma unroll
    for (int r = 0; r < 4; ++r) {
      int p = p0 + 16 + grp * 4 + r;
      float v = s[r] + bb;
      if (MODE == 0) {
        v = (v >= 0.f) ? v : 0.1f * v;
        outb[(size_t)p * 64 + ch] = f2bf(v);
      } else {
        out32[(size_t)ch * P_ + p] = v + resid[(size_t)ch * P_ + p];
      }
    }
  }
}

extern "C" void kernel_launch(void* const* d_in, const int* in_sizes, int n_in,
                              void* d_out, int out_size, void* d_ws, size_t ws_size,
                              hipStream_t stream) {
  const float* x      = (const float*)d_in[0];
  const float* w_off0 = (const float*)d_in[1];
  const float* b_off0 = (const float*)d_in[2];
  const float* w0     = (const float*)d_in[3];
  const float* b0     = (const float*)d_in[4];
  const float* w_off1 = (const float*)d_in[5];
  const float* b_off1 = (const float*)d_in[6];
  const float* w1     = (const float*)d_in[7];
  const float* b1     = (const float*)d_in[8];
  float* out = (float*)d_out;

  char* base = (char*)d_ws;
  unsigned short* x_clb = (unsigned short*)base;               // 2,064,384 B
  unsigned short* h_clb = (unsigned short*)(base + 2064384);   // 2,064,384 B
  float*          offt2 = (float*)(base + 4128768);            // 3,483,648 B
  unsigned short* wA0   = (unsigned short*)(base + 7612416);   // 221,184 B
  unsigned short* wA1   = (unsigned short*)(base + 7833600);
  unsigned short* wB0   = (unsigned short*)(base + 8054784);
  unsigned short* wB1   = (unsigned short*)(base + 8275968);   // end ~8.5 MB

  // static LDS in k_samp_l1 = 34816 B; + 49152 dynamic = 83968 B -> 1 block/CU
  const int pad_lds = 49152;

  hipLaunchKernelGGL(k_prep_x, dim3(252), dim3(256), 0, stream, x, x_clb);
  hipLaunchKernelGGL(k_prep_w4, dim3(432, 4), dim3(256), 0, stream,
                     w_off0, w_off1, w0, w1, wA0, wA1, wB0, wB1);

  // layer 0
  hipLaunchKernelGGL(k_off4w, dim3(504), dim3(256), 0, stream, x_clb, wA0, b_off0, offt2);
  hipLaunchKernelGGL((k_samp_l1<0>), dim3(504), dim3(256), pad_lds, stream,
                     x_clb, offt2, wB0, b0, (const float*)nullptr, (float*)nullptr, h_clb);

  // layer 1
  hipLaunchKernelGGL(k_off4w, dim3(504), dim3(256), 0, stream, h_clb, wA1, b_off1, offt2);
  hipLaunchKernelGGL((k_samp_l1<1>), dim3(504), dim3(256), pad_lds, stream,
                     h_clb, offt2, wB1, b1, x, out, (unsigned short*)nullptr);
}

// Round 12
// 97.571 us; speedup vs baseline: 1.2725x; 1.2725x over previous
//
#include <hip/hip_runtime.h>

#define T_ 7
#define H_ 48
#define W_ 48
#define P_ 16128      // T_*H_*W_
#define HW_ 2304
#define WROWS_ 7
#define NCHP_ (WROWS_ * 48 * 8)   // 2688 16B chunks = 43008 B

typedef __attribute__((ext_vector_type(8))) short short8;
typedef __attribute__((ext_vector_type(4))) float f32x4;
typedef __attribute__((ext_vector_type(2))) float f32x2;
typedef __attribute__((ext_vector_type(4))) unsigned u32x4;

__device__ __forceinline__ unsigned short f2bf(float f) {
  union { float f; unsigned u; } x{f};
  unsigned r = x.u + 0x7FFFu + ((x.u >> 16) & 1u);
  return (unsigned short)(r >> 16);
}
__device__ __forceinline__ float blo(unsigned u) {
  union { unsigned u; float f; } x{u << 16};
  return x.f;
}
__device__ __forceinline__ float bhi(unsigned u) {
  union { unsigned u; float f; } x{u & 0xFFFF0000u};
  return x.f;
}
__device__ __forceinline__ unsigned pack2(float a, float b) {
  return (unsigned)f2bf(a) | ((unsigned)f2bf(b) << 16);
}
__device__ __forceinline__ int xcd_swz(int bid, int nwg) {
  int cpx = nwg >> 3;
  return (bid & 7) * cpx + (bid >> 3);
}

struct Wgt { short8 b00, b01, b10, b11, b20, b21, b30, b31; };

__device__ __forceinline__ Wgt load_w(const unsigned short* base, int k, int lane) {
  const unsigned short* wp = base + (size_t)k * 4096 + lane * 8;
  Wgt w;
  w.b00 = *(const short8*)(wp);
  w.b01 = *(const short8*)(wp + 512);
  w.b10 = *(const short8*)(wp + 1024);
  w.b11 = *(const short8*)(wp + 1536);
  w.b20 = *(const short8*)(wp + 2048);
  w.b21 = *(const short8*)(wp + 2560);
  w.b30 = *(const short8*)(wp + 3072);
  w.b31 = *(const short8*)(wp + 3584);
  return w;
}

__device__ __forceinline__ Wgt load_w_nt(const unsigned short* base, int k, int lane) {
  const short8* wp = (const short8*)(base + (size_t)k * 4096 + lane * 8);
  Wgt w;
  w.b00 = __builtin_nontemporal_load(wp);
  w.b01 = __builtin_nontemporal_load(wp + 64);
  w.b10 = __builtin_nontemporal_load(wp + 128);
  w.b11 = __builtin_nontemporal_load(wp + 192);
  w.b20 = __builtin_nontemporal_load(wp + 256);
  w.b21 = __builtin_nontemporal_load(wp + 320);
  w.b30 = __builtin_nontemporal_load(wp + 384);
  w.b31 = __builtin_nontemporal_load(wp + 448);
  return w;
}

__device__ __forceinline__ void mfma8(const Wgt& W, short8 af0, short8 af1,
                                      f32x4& c0, f32x4& c1, f32x4& c2, f32x4& c3) {
  c0 = __builtin_amdgcn_mfma_f32_16x16x32_bf16(af0, W.b00, c0, 0, 0, 0);
  c0 = __builtin_amdgcn_mfma_f32_16x16x32_bf16(af1, W.b01, c0, 0, 0, 0);
  c1 = __builtin_amdgcn_mfma_f32_16x16x32_bf16(af0, W.b10, c1, 0, 0, 0);
  c1 = __builtin_amdgcn_mfma_f32_16x16x32_bf16(af1, W.b11, c1, 0, 0, 0);
  c2 = __builtin_amdgcn_mfma_f32_16x16x32_bf16(af0, W.b20, c2, 0, 0, 0);
  c2 = __builtin_amdgcn_mfma_f32_16x16x32_bf16(af1, W.b21, c2, 0, 0, 0);
  c3 = __builtin_amdgcn_mfma_f32_16x16x32_bf16(af0, W.b30, c3, 0, 0, 0);
  c3 = __builtin_amdgcn_mfma_f32_16x16x32_bf16(af1, W.b31, c3, 0, 0, 0);
}

// ---------- x [64][P] fp32 -> x_clb [P][64] bf16 ----------
__global__ void k_prep_x(const float* __restrict__ in, unsigned short* __restrict__ outb) {
  __shared__ float tile[64][65];
  int p0 = blockIdx.x * 64;
  int l = threadIdx.x & 63;
  int g = threadIdx.x >> 6;
#pragma unroll
  for (int i = 0; i < 16; ++i) {
    int c = g * 16 + i;
    tile[c][l] = in[c * P_ + p0 + l];
  }
  __syncthreads();
#pragma unroll
  for (int i = 0; i < 16; ++i) {
    int p = g * 16 + i;
    outb[(p0 + p) * 64 + l] = f2bf(tile[l][p]);
  }
}

// ---------- weights [OC][64][27] fp32 -> fragment-swizzled bf16 ----------
__global__ void k_prep_w4(const float* __restrict__ s0, const float* __restrict__ s1,
                          const float* __restrict__ s2, const float* __restrict__ s3,
                          unsigned short* __restrict__ d0, unsigned short* __restrict__ d1,
                          unsigned short* __restrict__ d2, unsigned short* __restrict__ d3) {
  int y = blockIdx.y;
  const float* w = (y == 0) ? s0 : (y == 1) ? s1 : (y == 2) ? s2 : s3;
  unsigned short* wt = (y == 0) ? d0 : (y == 1) ? d1 : (y == 2) ? d2 : d3;
  int OC = (y < 2) ? 54 : 64;
  int idx = blockIdx.x * 256 + threadIdx.x;   // < 110592
  int j = idx & 7;
  int l = (idx >> 3) & 63;
  int kc = (idx >> 9) & 1;
  int nt = (idx >> 10) & 3;
  int k = idx >> 12;
  int o = nt * 16 + (l & 15);
  int c = kc * 32 + (l >> 4) * 8 + j;
  wt[idx] = (o < OC) ? f2bf(w[(o * 64 + c) * 27 + k]) : (unsigned short)0;
}

// ---------- offset conv (R8-proven, unchanged) ----------
__global__ __launch_bounds__(256) void k_off4w(const unsigned short* __restrict__ xclb,
                                               const unsigned short* __restrict__ wAs,
                                               const float* __restrict__ boff,
                                               float* __restrict__ offt2) {
  __shared__ f32x4 red[4][4][64];
  int p0 = xcd_swz(blockIdx.x, gridDim.x) * 32;
  int t = p0 / HW_;
  int r0 = p0 - t * HW_;
  int h0r = r0 / W_;
  int w0s = r0 - h0r * W_;
  int h1r = h0r + (w0s == 32 ? 1 : 0);
  int w1s = (w0s == 32) ? 0 : w0s + 16;
  int tid = threadIdx.x;
  int lane = tid & 63, wid = tid >> 6;
  int pt = lane & 15, grp = lane >> 4;

  f32x4 zacc{0.f, 0.f, 0.f, 0.f};
  f32x4 aA0 = zacc, aA1 = zacc, aA2 = zacc, aA3 = zacc;
  f32x4 aB0 = zacc, aB1 = zacc, aB2 = zacc, aB3 = zacc;
  const short8 zero8{0, 0, 0, 0, 0, 0, 0, 0};
  int kbeg = wid * 7;

#pragma unroll
  for (int kk = 0; kk < 7; ++kk) {
    int kraw = kbeg + kk;
    int k = min(kraw, 26);
    int kt = k / 9;
    int r9 = k - kt * 9;
    int kh = r9 / 3;
    int kw = r9 - (r9 / 3) * 3;
    int t2 = t + kt - 1;
    bool tok = (kraw < 27) & ((unsigned)t2 < (unsigned)T_);
    int t2c = min(max(t2, 0), T_ - 1);

    Wgt W = load_w(wAs, k, lane);
    {
      int h2 = h0r + kh - 1;
      int w2 = w0s + pt + kw - 1;
      bool ok = tok & ((unsigned)h2 < (unsigned)H_) & ((unsigned)w2 < (unsigned)W_);
      int h2c = min(max(h2, 0), H_ - 1);
      int w2c = min(max(w2, 0), W_ - 1);
      const unsigned short* ap = xclb + ((size_t)(t2c * HW_ + h2c * W_ + w2c) * 64 + grp * 8);
      short8 a0 = *(const short8*)ap;
      short8 a1 = *(const short8*)(ap + 32);
      a0 = ok ? a0 : zero8;
      a1 = ok ? a1 : zero8;
      mfma8(W, a0, a1, aA0, aA1, aA2, aA3);
    }
    {
      int h2 = h1r + kh - 1;
      int w2 = w1s + pt + kw - 1;
      bool ok = tok & ((unsigned)h2 < (unsigned)H_) & ((unsigned)w2 < (unsigned)W_);
      int h2c = min(max(h2, 0), H_ - 1);
      int w2c = min(max(w2, 0), W_ - 1);
      const unsigned short* ap = xclb + ((size_t)(t2c * HW_ + h2c * W_ + w2c) * 64 + grp * 8);
      short8 a0 = *(const short8*)ap;
      short8 a1 = *(const short8*)(ap + 32);
      a0 = ok ? a0 : zero8;
      a1 = ok ? a1 : zero8;
      mfma8(W, a0, a1, aB0, aB1, aB2, aB3);
    }
  }

  int oc = wid * 16 + pt;
  float bb = (oc < 54) ? boff[oc] : 0.f;
  int kidx = oc >> 1, d = oc & 1;

  red[wid][0][lane] = aA0;
  red[wid][1][lane] = aA1;
  red[wid][2][lane] = aA2;
  red[wid][3][lane] = aA3;
  __syncthreads();
  {
    f32x4 s = red[0][wid][lane];
    s = s + red[1][wid][lane];
    s = s + red[2][wid][lane];
    s = s + red[3][wid][lane];
    if (oc < 54) {
#pragma unroll
      for (int r = 0; r < 4; ++r) {
        int p = p0 + grp * 4 + r;
        offt2[((size_t)kidx * P_ + p) * 2 + d] = s[r] + bb;
      }
    }
  }
  __syncthreads();
  red[wid][0][lane] = aB0;
  red[wid][1][lane] = aB1;
  red[wid][2][lane] = aB2;
  red[wid][3][lane] = aB3;
  __syncthreads();
  {
    f32x4 s = red[0][wid][lane];
    s = s + red[1][wid][lane];
    s = s + red[2][wid][lane];
    s = s + red[3][wid][lane];
    if (oc < 54) {
#pragma unroll
      for (int r = 0; r < 4; ++r) {
        int p = p0 + 16 + grp * 4 + r;
        offt2[((size_t)kidx * P_ + p) * 2 + d] = s[r] + bb;
      }
    }
  }
}

// ---------- deformable sample + conv: 7x48 swizzled LDS window, 2 blocks/CU ----------
template <int MODE>
__global__ __launch_bounds__(256) void k_samp_w(
    const unsigned short* __restrict__ xclb, const float* __restrict__ offt2,
    const unsigned short* __restrict__ wBs, const float* __restrict__ bias,
    const float* __restrict__ resid, float* __restrict__ out32,
    unsigned short* __restrict__ outb) {
  extern __shared__ u32x4 xs[];                 // 2688 x 16B window
  __shared__ f32x4 red[4][4][64];
  __shared__ unsigned short sA[4][2][16][72];
  int p0 = xcd_swz(blockIdx.x, gridDim.x) * 32;
  int t = p0 / HW_;
  int r0 = p0 - t * HW_;
  int h0r = r0 / W_;
  int w0s = r0 - h0r * W_;
  int h1r = h0r + (w0s == 32 ? 1 : 0);
  int w1s = (w0s == 32) ? 0 : w0s + 16;
  int lo = h0r - 2;                             // window rows lo..lo+6
  int tid = threadIdx.x;
  int lane = tid & 63, wid = tid >> 6;
  int pt = lane & 15, grp = lane >> 4;

  f32x4 zacc{0.f, 0.f, 0.f, 0.f};
  f32x4 aA0 = zacc, aA1 = zacc, aA2 = zacc, aA3 = zacc;
  f32x4 aB0 = zacc, aB1 = zacc, aB2 = zacc, aB3 = zacc;

  for (int kt = 0; kt < 3; ++kt) {
    int t2 = t + kt - 1;
    bool pvalid = (unsigned)t2 < (unsigned)T_;  // block-uniform
    __syncthreads();                            // prior plane's reads complete
    if (pvalid) {
      for (int q = tid; q < NCHP_; q += 256) {
        int pidx = q >> 3;
        int sub = q & 7;
        int r = pidx / 48;
        int c = pidx - r * 48;
        int srow = min(max(lo + r, 0), H_ - 1);
        const u32x4* src = (const u32x4*)(xclb + (size_t)(t2 * HW_ + srow * W_ + c) * 64);
        xs[(pidx << 3) + (sub ^ (c & 7))] = src[sub];
      }
    }
    __syncthreads();                            // window visible
    if (pvalid) {
      int cls = (wid + kt) & 3;                 // rotation-balanced tap classes
#pragma unroll
      for (int u = 0; u < 3; ++u) {
        int jc = cls + 4 * u;
        if (jc < 9) {                           // wave-uniform
          int kh = jc / 3;
          int kw = jc - (jc / 3) * 3;
          int kk = kt * 9 + jc;
          Wgt W = load_w_nt(wBs, kk, lane);
#pragma unroll
          for (int f = 0; f < 2; ++f) {
            int hrow = f ? h1r : h0r;
            int wst = f ? w1s : w0s;
            f32x2 o2 = __builtin_nontemporal_load(
                (const f32x2*)(offt2 + ((size_t)kk * P_ + p0 + f * 16 + pt) * 2));
            float ph = (float)(hrow + kh - 1) + o2.x;
            float pw = (float)(wst + pt + kw - 1) + o2.y;
            float hf = floorf(ph), wf = floorf(pw);
            float lh = ph - hf, lw = pw - wf;
            int h0 = (int)hf, w0i = (int)wf;
            int h1 = h0 + 1, w1 = w0i + 1;
            bool h0ok = ((unsigned)h0 < (unsigned)H_), h1ok = ((unsigned)h1 < (unsigned)H_);
            bool w0ok = ((unsigned)w0i < (unsigned)W_), w1ok = ((unsigned)w1 < (unsigned)W_);
            int h0c = min(max(h0, 0), H_ - 1), h1c = min(max(h1, 0), H_ - 1);
            int w0c = min(max(w0i, 0), W_ - 1), w1c = min(max(w1, 0), W_ - 1);
            float omlh = 1.f - lh, omlw = 1.f - lw;
            float g00 = (h0ok & w0ok) ? omlh * omlw : 0.f;
            float g01 = (h0ok & w1ok) ? omlh * lw : 0.f;
            float g10 = (h1ok & w0ok) ? lh * omlw : 0.f;
            float g11 = (h1ok & w1ok) ? lh * lw : 0.f;

            // LDS window gather (swizzled); fallback to global if row out of apron
            int pr0 = h0c - lo, pr1 = h1c - lo;
            bool inw = ((unsigned)pr0 < (unsigned)WROWS_) & ((unsigned)pr1 < (unsigned)WROWS_);
            int pr0c = min(max(pr0, 0), WROWS_ - 1), pr1c = min(max(pr1, 0), WROWS_ - 1);
            int b00 = (pr0c * 48 + w0c) << 3, b01 = (pr0c * 48 + w1c) << 3;
            int b10 = (pr1c * 48 + w0c) << 3, b11 = (pr1c * 48 + w1c) << 3;
            int s0x = w0c & 7, s1x = w1c & 7;
            int e0 = 2 * grp, e1 = 2 * grp + 1;
            u32x4 A0 = xs[b00 + (e0 ^ s0x)], A1 = xs[b00 + (e1 ^ s0x)];
            u32x4 B0 = xs[b01 + (e0 ^ s1x)], B1 = xs[b01 + (e1 ^ s1x)];
            u32x4 C0 = xs[b10 + (e0 ^ s0x)], C1 = xs[b10 + (e1 ^ s0x)];
            u32x4 D0 = xs[b11 + (e0 ^ s1x)], D1 = xs[b11 + (e1 ^ s1x)];
            if (!__all(inw ? 1 : 0)) {          // cold: offset beyond apron
              if (!inw) {
                const unsigned short* bt = xclb + (size_t)(t2 * HW_) * 64 + grp * 16;
                int i00 = (h0c * W_ + w0c) * 64, i01 = (h0c * W_ + w1c) * 64;
                int i10 = (h1c * W_ + w0c) * 64, i11 = (h1c * W_ + w1c) * 64;
                A0 = *(const u32x4*)(bt + i00);  A1 = *(const u32x4*)(bt + i00 + 8);
                B0 = *(const u32x4*)(bt + i01);  B1 = *(const u32x4*)(bt + i01 + 8);
                C0 = *(const u32x4*)(bt + i10);  C1 = *(const u32x4*)(bt + i10 + 8);
                D0 = *(const u32x4*)(bt + i11);  D1 = *(const u32x4*)(bt + i11 + 8);
              }
            }

#define LERPU(a, b, c, d)                                                   \
  pack2(g00 * blo(a) + g01 * blo(b) + g10 * blo(c) + g11 * blo(d),          \
        g00 * bhi(a) + g01 * bhi(b) + g10 * bhi(c) + g11 * bhi(d))
            u32x4 v0, v1;
            v0[0] = LERPU(A0[0], B0[0], C0[0], D0[0]);
            v0[1] = LERPU(A0[1], B0[1], C0[1], D0[1]);
            v0[2] = LERPU(A0[2], B0[2], C0[2], D0[2]);
            v0[3] = LERPU(A0[3], B0[3], C0[3], D0[3]);
            v1[0] = LERPU(A1[0], B1[0], C1[0], D1[0]);
            v1[1] = LERPU(A1[1], B1[1], C1[1], D1[1]);
            v1[2] = LERPU(A1[2], B1[2], C1[2], D1[2]);
            v1[3] = LERPU(A1[3], B1[3], C1[3], D1[3]);
#undef LERPU

            __builtin_amdgcn_wave_barrier();
            *(u32x4*)&sA[wid][f][pt][grp * 16] = v0;
            *(u32x4*)&sA[wid][f][pt][grp * 16 + 8] = v1;
            __builtin_amdgcn_wave_barrier();    // same-wave LDS in-order
            short8 af0 = *(const short8*)&sA[wid][f][pt][grp * 8];
            short8 af1 = *(const short8*)&sA[wid][f][pt][32 + grp * 8];
            __builtin_amdgcn_wave_barrier();

            if (f == 0) mfma8(W, af0, af1, aA0, aA1, aA2, aA3);
            else        mfma8(W, af0, af1, aB0, aB1, aB2, aB3);
          }
        }
      }
    }
  }

  int ch = wid * 16 + pt;
  float bb = bias[ch];

  red[wid][0][lane] = aA0;
  red[wid][1][lane] = aA1;
  red[wid][2][lane] = aA2;
  red[wid][3][lane] = aA3;
  __syncthreads();
  {
    f32x4 s = red[0][wid][lane];
    s = s + red[1][wid][lane];
    s = s + red[2][wid][lane];
    s = s + red[3][wid][lane];
#pragma unroll
    for (int r = 0; r < 4; ++r) {
      int p = p0 + grp * 4 + r;
      float v = s[r] + bb;
      if (MODE == 0) {
        v = (v >= 0.f) ? v : 0.1f * v;
        outb[(size_t)p * 64 + ch] = f2bf(v);
      } else {
        out32[(size_t)ch * P_ + p] = v + resid[(size_t)ch * P_ + p];
      }
    }
  }
  __syncthreads();
  red[wid][0][lane] = aB0;
  red[wid][1][lane] = aB1;
  red[wid][2][lane] = aB2;
  red[wid][3][lane] = aB3;
  __syncthreads();
  {
    f32x4 s = red[0][wid][lane];
    s = s + red[1][wid][lane];
    s = s + red[2][wid][lane];
    s = s + red[3][wid][lane];
#pragma unroll
    for (int r = 0; r < 4; ++r) {
      int p = p0 + 16 + grp * 4 + r;
      float v = s[r] + bb;
      if (MODE == 0) {
        v = (v >= 0.f) ? v : 0.1f * v;
        outb[(size_t)p * 64 + ch] = f2bf(v);
      } else {
        out32[(size_t)ch * P_ + p] = v + resid[(size_t)ch * P_ + p];
      }
    }
  }
}

extern "C" void kernel_launch(void* const* d_in, const int* in_sizes, int n_in,
                              void* d_out, int out_size, void* d_ws, size_t ws_size,
                              hipStream_t stream) {
  const float* x      = (const float*)d_in[0];
  const float* w_off0 = (const float*)d_in[1];
  const float* b_off0 = (const float*)d_in[2];
  const float* w0     = (const float*)d_in[3];
  const float* b0     = (const float*)d_in[4];
  const float* w_off1 = (const float*)d_in[5];
  const float* b_off1 = (const float*)d_in[6];
  const float* w1     = (const float*)d_in[7];
  const float* b1     = (const float*)d_in[8];
  float* out = (float*)d_out;

  char* base = (char*)d_ws;
  unsigned short* x_clb = (unsigned short*)base;               // 2,064,384 B
  unsigned short* h_clb = (unsigned short*)(base + 2064384);   // 2,064,384 B
  float*          offt2 = (float*)(base + 4128768);            // 3,483,648 B
  unsigned short* wA0   = (unsigned short*)(base + 7612416);   // 221,184 B
  unsigned short* wA1   = (unsigned short*)(base + 7833600);
  unsigned short* wB0   = (unsigned short*)(base + 8054784);
  unsigned short* wB1   = (unsigned short*)(base + 8275968);   // end ~8.5 MB

  const int win_lds = NCHP_ * 16;   // 43008 B; + 20992 static = 64000 -> 2 blocks/CU

  hipLaunchKernelGGL(k_prep_x, dim3(252), dim3(256), 0, stream, x, x_clb);
  hipLaunchKernelGGL(k_prep_w4, dim3(432, 4), dim3(256), 0, stream,
                     w_off0, w_off1, w0, w1, wA0, wA1, wB0, wB1);

  // layer 0
  hipLaunchKernelGGL(k_off4w, dim3(504), dim3(256), 0, stream, x_clb, wA0, b_off0, offt2);
  hipLaunchKernelGGL((k_samp_w<0>), dim3(504), dim3(256), win_lds, stream,
                     x_clb, offt2, wB0, b0, (const float*)nullptr, (float*)nullptr, h_clb);

  // layer 1
  hipLaunchKernelGGL(k_off4w, dim3(504), dim3(256), 0, stream, h_clb, wA1, b_off1, offt2);
  hipLaunchKernelGGL((k_samp_w<1>), dim3(504), dim3(256), win_lds, stream,
                     h_clb, offt2, wB1, b1, x, out, (unsigned short*)nullptr);
}